// Round 6
// baseline (226.664 us; speedup 1.0000x reference)
//
#include <hip/hip_runtime.h>
#include <hip/hip_cooperative_groups.h>
#include <stdint.h>

namespace cg = cooperative_groups;

// Problem constants
#define CHELEM 131072        // 2048*64 elements per chunk (flat-reshape chunk)

typedef __attribute__((ext_vector_type(4))) float   f32x4;
typedef __attribute__((ext_vector_type(8))) short   bh8;     // 8 bf16 in 4 VGPRs
typedef __attribute__((ext_vector_type(4))) unsigned short u16x4;
typedef unsigned short u16;

__device__ inline u16 f2bf(float f) {
    union { float f; uint32_t u; } v; v.f = f;
    uint32_t u = v.u;
    u += 0x7FFF + ((u >> 16) & 1);         // RNE
    return (u16)(u >> 16);
}
__device__ inline float bf2f(u16 h) {
    union { uint32_t u; float f; } v; v.u = ((uint32_t)h) << 16;
    return v.f;
}

__device__ inline void gload_lds16(const u16* g, u16* l) {
    __builtin_amdgcn_global_load_lds(
        (const __attribute__((address_space(1))) uint32_t*)g,
        (__attribute__((address_space(3)))       uint32_t*)l,
        16, 0, 0);
}

// ================= Fused cooperative kernel =================
// 384 blocks x 256 threads; __launch_bounds__(256,2) caps VGPR<=256 so the
// runtime's co-residency check passes (2 blocks/CU x 256 CU = 512 >= 384).
// Phase bodies verbatim from the proven 47.6us 5-kernel config.
__global__ __launch_bounds__(256, 2) void fused_mha(
        const float* __restrict__ x,
        const float* __restrict__ Wq, const float* __restrict__ bq,
        const float* __restrict__ Wk, const float* __restrict__ bk,
        const float* __restrict__ Wv, const float* __restrict__ bv,
        u16* __restrict__ xb, u16* __restrict__ Wb,
        u16* __restrict__ Qb, u16* __restrict__ Kb, u16* __restrict__ Vb,
        float* __restrict__ part, u16* __restrict__ Pb,
        float* __restrict__ outp) {
    cg::grid_group grid = cg::this_grid();
    __shared__ u16 smem[16384];                 // 32KB, carved per phase
    const int tid = threadIdx.x;
    const int bid = blockIdx.x;
    const int lane = tid & 63;

    // ---------------- P0: fp32 -> bf16 convert (x, Wq, Wk, Wv) ----------------
    {
        const int gidx = bid * 256 + tid;       // 98304 threads, 720896 float4s
#pragma unroll
        for (int it = 0; it < 8; ++it) {
            const int idx = gidx + it * 98304;
            if (idx < 720896) {
                const float4* src; u16* dst; int off;
                if (idx < 524288) { src = (const float4*)x; dst = xb; off = idx; }
                else {
                    int j = idx - 524288;
                    int w = j >> 16;
                    off = j & 65535;
                    src = (const float4*)(w == 0 ? Wq : (w == 1 ? Wk : Wv));
                    dst = Wb + w * 262144;
                }
                float4 f = src[off];
                u16x4 o;
                o[0] = f2bf(f.x); o[1] = f2bf(f.y); o[2] = f2bf(f.z); o[3] = f2bf(f.w);
                *(u16x4*)(dst + off * 4) = o;
            }
        }
    }
    grid.sync();

    // ---------------- P1: QKV projection GEMM (gemm_bt, 128x128 tile, BK=64) ----------------
    {
        u16* lA = smem;
        u16* lB = smem + 8192;
        const int wid = tid >> 6;
        const int wrow = wid >> 1, wcol = wid & 1;
        const int swz = (bid & 7) * 48 + (bid >> 3);   // XCD swizzle
        const int mb = swz / 12, nb = swz % 12;
        const int w    = nb >> 2;
        const int nloc = (nb & 3) * 128;
        const u16*   W    = Wb + w * 262144;
        const float* bias = (w == 0) ? bq : ((w == 1) ? bk : bv);
        u16*         out  = (w == 0) ? Qb : ((w == 1) ? Kb : Vb);
        const int m0 = mb * 128;

        f32x4 acc[4][4] = {};
        const int srow = tid >> 3;
        const int scol = (tid & 7) * 8;

        for (int kb = 0; kb < 8; ++kb) {
            __syncthreads();
            const int k0 = kb * 64;
#pragma unroll
            for (int it = 0; it < 4; ++it) {
                int r = it * 32 + srow;
                gload_lds16(xb + (size_t)(m0 + r) * 512 + k0 + scol,   lA + r * 64 + scol);
                gload_lds16(W  + (size_t)(nloc + r) * 512 + k0 + scol, lB + r * 64 + scol);
            }
            asm volatile("s_waitcnt vmcnt(0)" ::: "memory");
            __syncthreads();
#pragma unroll
            for (int ks = 0; ks < 2; ++ks) {
                const int kk = ks * 32 + (lane >> 4) * 8;
                bh8 a[4], b[4];
#pragma unroll
                for (int i = 0; i < 4; ++i) {
                    a[i] = *(const bh8*)&lA[(wrow * 64 + i * 16 + (lane & 15)) * 64 + kk];
                    b[i] = *(const bh8*)&lB[(wcol * 64 + i * 16 + (lane & 15)) * 64 + kk];
                }
#pragma unroll
                for (int i = 0; i < 4; ++i)
#pragma unroll
                    for (int j = 0; j < 4; ++j)
                        acc[i][j] = __builtin_amdgcn_mfma_f32_16x16x32_bf16(a[i], b[j], acc[i][j], 0, 0, 0);
            }
        }
#pragma unroll
        for (int i = 0; i < 4; ++i) {
            const int row_base = m0 + wrow * 64 + i * 16 + ((lane >> 4) * 4);
#pragma unroll
            for (int j = 0; j < 4; ++j) {
                const int col = nloc + wcol * 64 + j * 16 + (lane & 15);
                const float bv_ = bias[col];
#pragma unroll
                for (int r = 0; r < 4; ++r)
                    out[(size_t)(row_base + r) * 512 + col] = f2bf(acc[i][j][r] + bv_);
            }
        }
    }
    grid.sync();

    // ---------------- P2: partials part[(c*16+s)][d][e] = sum_r V_c[r][d] K_c[r][e] ----------------
    if (bid < 256) {
        u16* lK = smem;
        u16* lV = smem + 4096;
        const int c = bid >> 4;
        const int s = bid & 15;
        const int e4 = (tid & 15) * 4;
        const int d4 = (tid >> 4) * 4;
        float acc[4][4] = {};
        const int base = c * CHELEM + s * 8192;

        for (int step = 0; step < 2; ++step) {
            __syncthreads();
            const int tb = base + step * 4096;
            gload_lds16(Kb + tb + tid * 8,        lK + tid * 8);
            gload_lds16(Kb + tb + 2048 + tid * 8, lK + 2048 + tid * 8);
            gload_lds16(Vb + tb + tid * 8,        lV + tid * 8);
            gload_lds16(Vb + tb + 2048 + tid * 8, lV + 2048 + tid * 8);
            asm volatile("s_waitcnt vmcnt(0)" ::: "memory");
            __syncthreads();
#pragma unroll 8
            for (int r = 0; r < 64; ++r) {
                u16x4 ku = *(const u16x4*)&lK[r * 64 + e4];
                u16x4 vu = *(const u16x4*)&lV[r * 64 + d4];
                float kf[4] = {bf2f(ku[0]), bf2f(ku[1]), bf2f(ku[2]), bf2f(ku[3])};
                float vf[4] = {bf2f(vu[0]), bf2f(vu[1]), bf2f(vu[2]), bf2f(vu[3])};
#pragma unroll
                for (int j = 0; j < 4; ++j)
#pragma unroll
                    for (int i = 0; i < 4; ++i)
                        acc[j][i] += vf[j] * kf[i];
            }
        }
        float* dst = part + (size_t)bid * 4096;
#pragma unroll
        for (int j = 0; j < 4; ++j)
#pragma unroll
            for (int i = 0; i < 4; ++i)
                dst[(d4 + j) * 64 + (e4 + i)] = acc[j][i];
    }
    grid.sync();

    // ---------------- P3: reduce partials + scale -> Pb bf16 [16][64][64] ----------------
    if (bid < 64) {
        const int idx = bid * 256 + tid;
        const int c = idx >> 10;
        const int off = (idx & 1023) * 4;
        f32x4 acc = {0.f, 0.f, 0.f, 0.f};
#pragma unroll
        for (int s = 0; s < 16; ++s)
            acc += *(const f32x4*)&part[(size_t)(c * 16 + s) * 4096 + off];
        u16x4 o;
#pragma unroll
        for (int j = 0; j < 4; ++j) o[j] = f2bf(acc[j] * 0.125f);   // scale = DIM^-0.5
        *(u16x4*)&Pb[c * 4096 + off] = o;
    }
    grid.sync();

    // ---------------- P4: out_c = Q_c @ P_c^T  (K=64 per head, no LDS) ----------------
    if (bid < 128) {
        const int w = tid >> 6;
        const int bb = bid >> 6;
        const int ib = bid & 63;
        const int i0 = ib * 32 + (w >> 1) * 16;
        const int dbase = (w & 1) * 32;
        const int krow = lane & 15;
        const int koff = (lane >> 4) * 8;

        f32x4 acc[8][2] = {};
#pragma unroll
        for (int h = 0; h < 8; ++h) {
            const int c = h * 2 + bb;
            const u16* Qc = Qb + (size_t)c * CHELEM;
            const u16* Pc = Pb + c * 4096;
#pragma unroll
            for (int ks = 0; ks < 2; ++ks) {
                bh8 a = *(const bh8*)&Qc[(i0 + krow) * 64 + ks * 32 + koff];
#pragma unroll
                for (int nf = 0; nf < 2; ++nf) {
                    bh8 b = *(const bh8*)&Pc[(dbase + nf * 16 + krow) * 64 + ks * 32 + koff];
                    acc[h][nf] = __builtin_amdgcn_mfma_f32_16x16x32_bf16(a, b, acc[h][nf], 0, 0, 0);
                }
            }
        }
        const int orow_base = bb * 2048 + ib * 32 + (w >> 1) * 16 + (lane >> 4) * 4;
#pragma unroll
        for (int nf = 0; nf < 2; ++nf) {
            const int d = dbase + nf * 16 + (lane & 15);
#pragma unroll
            for (int r = 0; r < 4; ++r) {
                f32x4 lo = {acc[0][nf][r], acc[1][nf][r], acc[2][nf][r], acc[3][nf][r]};
                f32x4 hi = {acc[4][nf][r], acc[5][nf][r], acc[6][nf][r], acc[7][nf][r]};
                float* dst = outp + (size_t)(orow_base + r) * 512 + d * 8;
                *(f32x4*)dst = lo;
                *(f32x4*)(dst + 4) = hi;
            }
        }
    }
}

// ================= Fallback path: the proven R2 five-kernel config =================
__global__ __launch_bounds__(256) void k0_convert(
        const float* __restrict__ x,
        const float* __restrict__ Wq,
        const float* __restrict__ Wk,
        const float* __restrict__ Wv,
        u16* __restrict__ xb, u16* __restrict__ Wb) {
    int idx = blockIdx.x * 256 + threadIdx.x;
    const float4* src; u16* dst; int off;
    if (idx < 524288) { src = (const float4*)x; dst = xb; off = idx; }
    else {
        int j = idx - 524288;
        int w = j >> 16;
        off = j & 65535;
        src = (const float4*)(w == 0 ? Wq : (w == 1 ? Wk : Wv));
        dst = Wb + w * 262144;
    }
    float4 f = src[off];
    u16x4 o;
    o[0] = f2bf(f.x); o[1] = f2bf(f.y); o[2] = f2bf(f.z); o[3] = f2bf(f.w);
    *(u16x4*)(dst + off * 4) = o;
}

__global__ __launch_bounds__(256) void k1_qkv(
        const u16* __restrict__ xb, const u16* __restrict__ Wb,
        const float* __restrict__ bq, const float* __restrict__ bk,
        const float* __restrict__ bv,
        u16* __restrict__ Qb, u16* __restrict__ Kb, u16* __restrict__ Vb) {
    __shared__ u16 lA[128 * 64];
    __shared__ u16 lB[128 * 64];
    const int tid  = threadIdx.x;
    const int lane = tid & 63, wid = tid >> 6;
    const int wrow = wid >> 1, wcol = wid & 1;
    const int swz  = (blockIdx.x & 7) * 48 + (blockIdx.x >> 3);
    const int mb = swz / 12, nb = swz % 12;
    const int w    = nb >> 2;
    const int nloc = (nb & 3) * 128;
    const u16*   W    = Wb + w * 262144;
    const float* bias = (w == 0) ? bq : ((w == 1) ? bk : bv);
    u16*         out  = (w == 0) ? Qb : ((w == 1) ? Kb : Vb);
    const int m0 = mb * 128;

    f32x4 acc[4][4] = {};
    const int srow = tid >> 3;
    const int scol = (tid & 7) * 8;

    for (int kb = 0; kb < 8; ++kb) {
        __syncthreads();
        const int k0 = kb * 64;
#pragma unroll
        for (int it = 0; it < 4; ++it) {
            int r = it * 32 + srow;
            gload_lds16(xb + (size_t)(m0 + r) * 512 + k0 + scol,  lA + r * 64 + scol);
            gload_lds16(W  + (size_t)(nloc + r) * 512 + k0 + scol, lB + r * 64 + scol);
        }
        asm volatile("s_waitcnt vmcnt(0)" ::: "memory");
        __syncthreads();
#pragma unroll
        for (int ks = 0; ks < 2; ++ks) {
            const int kk = ks * 32 + (lane >> 4) * 8;
            bh8 a[4], b[4];
#pragma unroll
            for (int i = 0; i < 4; ++i) {
                a[i] = *(const bh8*)&lA[(wrow * 64 + i * 16 + (lane & 15)) * 64 + kk];
                b[i] = *(const bh8*)&lB[(wcol * 64 + i * 16 + (lane & 15)) * 64 + kk];
            }
#pragma unroll
            for (int i = 0; i < 4; ++i)
#pragma unroll
                for (int j = 0; j < 4; ++j)
                    acc[i][j] = __builtin_amdgcn_mfma_f32_16x16x32_bf16(a[i], b[j], acc[i][j], 0, 0, 0);
        }
    }
#pragma unroll
    for (int i = 0; i < 4; ++i) {
        const int row_base = m0 + wrow * 64 + i * 16 + ((lane >> 4) * 4);
#pragma unroll
        for (int j = 0; j < 4; ++j) {
            const int col = nloc + wcol * 64 + j * 16 + (lane & 15);
            const float bv_ = bias[col];
#pragma unroll
            for (int r = 0; r < 4; ++r)
                out[(size_t)(row_base + r) * 512 + col] = f2bf(acc[i][j][r] + bv_);
        }
    }
}

__global__ __launch_bounds__(256) void k2a_partials(
        const u16* __restrict__ Kb, const u16* __restrict__ Vb,
        float* __restrict__ part) {
    __shared__ u16 lK[64 * 64];
    __shared__ u16 lV[64 * 64];
    const int tid = threadIdx.x;
    const int c = blockIdx.x >> 4;
    const int s = blockIdx.x & 15;
    const int e4 = (tid & 15) * 4;
    const int d4 = (tid >> 4) * 4;
    float acc[4][4] = {};
    const int base = c * CHELEM + s * 8192;

    for (int step = 0; step < 2; ++step) {
        __syncthreads();
        const int tb = base + step * 4096;
        gload_lds16(Kb + tb + tid * 8,        lK + tid * 8);
        gload_lds16(Kb + tb + 2048 + tid * 8, lK + 2048 + tid * 8);
        gload_lds16(Vb + tb + tid * 8,        lV + tid * 8);
        gload_lds16(Vb + tb + 2048 + tid * 8, lV + 2048 + tid * 8);
        asm volatile("s_waitcnt vmcnt(0)" ::: "memory");
        __syncthreads();
#pragma unroll 8
        for (int r = 0; r < 64; ++r) {
            u16x4 ku = *(const u16x4*)&lK[r * 64 + e4];
            u16x4 vu = *(const u16x4*)&lV[r * 64 + d4];
            float kf[4] = {bf2f(ku[0]), bf2f(ku[1]), bf2f(ku[2]), bf2f(ku[3])};
            float vf[4] = {bf2f(vu[0]), bf2f(vu[1]), bf2f(vu[2]), bf2f(vu[3])};
#pragma unroll
            for (int j = 0; j < 4; ++j)
#pragma unroll
                for (int i = 0; i < 4; ++i)
                    acc[j][i] += vf[j] * kf[i];
        }
    }
    float* dst = part + (size_t)blockIdx.x * 4096;
#pragma unroll
    for (int j = 0; j < 4; ++j)
#pragma unroll
        for (int i = 0; i < 4; ++i)
            dst[(d4 + j) * 64 + (e4 + i)] = acc[j][i];
}

__global__ __launch_bounds__(256) void k2b_reduce(
        const float* __restrict__ part, u16* __restrict__ Pb) {
    const int idx = blockIdx.x * 256 + threadIdx.x;
    const int c = idx >> 10;
    const int off = (idx & 1023) * 4;
    f32x4 acc = {0.f, 0.f, 0.f, 0.f};
#pragma unroll
    for (int s = 0; s < 16; ++s)
        acc += *(const f32x4*)&part[(size_t)(c * 16 + s) * 4096 + off];
    u16x4 o;
#pragma unroll
    for (int j = 0; j < 4; ++j) o[j] = f2bf(acc[j] * 0.125f);
    *(u16x4*)&Pb[c * 4096 + off] = o;
}

__global__ __launch_bounds__(256) void k3_out(
        const u16* __restrict__ Qb, const u16* __restrict__ Pb,
        float* __restrict__ outp) {
    const int tid = threadIdx.x;
    const int lane = tid & 63, w = tid >> 6;
    const int bb = blockIdx.x >> 6;
    const int ib = blockIdx.x & 63;
    const int i0 = ib * 32 + (w >> 1) * 16;
    const int dbase = (w & 1) * 32;
    const int krow = lane & 15;
    const int koff = (lane >> 4) * 8;

    f32x4 acc[8][2] = {};
#pragma unroll
    for (int h = 0; h < 8; ++h) {
        const int c = h * 2 + bb;
        const u16* Qc = Qb + (size_t)c * CHELEM;
        const u16* Pc = Pb + c * 4096;
#pragma unroll
        for (int ks = 0; ks < 2; ++ks) {
            bh8 a = *(const bh8*)&Qc[(i0 + krow) * 64 + ks * 32 + koff];
#pragma unroll
            for (int nf = 0; nf < 2; ++nf) {
                bh8 b = *(const bh8*)&Pc[(dbase + nf * 16 + krow) * 64 + ks * 32 + koff];
                acc[h][nf] = __builtin_amdgcn_mfma_f32_16x16x32_bf16(a, b, acc[h][nf], 0, 0, 0);
            }
        }
    }
    const int orow_base = bb * 2048 + ib * 32 + (w >> 1) * 16 + (lane >> 4) * 4;
#pragma unroll
    for (int nf = 0; nf < 2; ++nf) {
        const int d = dbase + nf * 16 + (lane & 15);
#pragma unroll
        for (int r = 0; r < 4; ++r) {
            f32x4 lo = {acc[0][nf][r], acc[1][nf][r], acc[2][nf][r], acc[3][nf][r]};
            f32x4 hi = {acc[4][nf][r], acc[5][nf][r], acc[6][nf][r], acc[7][nf][r]};
            float* dst = outp + (size_t)(orow_base + r) * 512 + d * 8;
            *(f32x4*)dst = lo;
            *(f32x4*)(dst + 4) = hi;
        }
    }
}

extern "C" void kernel_launch(void* const* d_in, const int* in_sizes, int n_in,
                              void* d_out, int out_size, void* d_ws, size_t ws_size,
                              hipStream_t stream) {
    const float* x  = (const float*)d_in[0];
    const float* Wq = (const float*)d_in[1];
    const float* bq = (const float*)d_in[2];
    const float* Wk = (const float*)d_in[3];
    const float* bk = (const float*)d_in[4];
    const float* Wv = (const float*)d_in[5];
    const float* bv = (const float*)d_in[6];
    float* outp = (float*)d_out;

    u16* xb = (u16*)d_ws;                 // 4096*512
    u16* Wb = xb + 2097152;               // 3*512*512
    u16* Qb = Wb + 786432;                // 4096*512 (flat)
    u16* Kb = Qb + 2097152;               // flat
    u16* Vb = Kb + 2097152;               // flat
    float* part = (float*)(Vb + 2097152); // 256*4096 floats
    u16* Pb = (u16*)(part + 1048576);     // 16*64*64

    void* args[] = {
        (void*)&x, (void*)&Wq, (void*)&bq, (void*)&Wk, (void*)&bk,
        (void*)&Wv, (void*)&bv, (void*)&xb, (void*)&Wb, (void*)&Qb,
        (void*)&Kb, (void*)&Vb, (void*)&part, (void*)&Pb, (void*)&outp
    };
    hipError_t err = hipLaunchCooperativeKernel((const void*)fused_mha,
                                                dim3(384), dim3(256),
                                                args, 0, stream);
    if (err != hipSuccess) {
        (void)hipGetLastError();   // clear sticky error so harness checks stay clean
        k0_convert<<<2816, 256, 0, stream>>>(x, Wq, Wk, Wv, xb, Wb);
        k1_qkv<<<384, 256, 0, stream>>>(xb, Wb, bq, bk, bv, Qb, Kb, Vb);
        k2a_partials<<<256, 256, 0, stream>>>(Kb, Vb, part);
        k2b_reduce<<<64, 256, 0, stream>>>(part, Pb);
        k3_out<<<128, 256, 0, stream>>>(Qb, Pb, outp);
    }
}

// Round 7
// 45.881 us; speedup vs baseline: 4.9402x; 4.9402x over previous
//
#include <hip/hip_runtime.h>
#include <stdint.h>

// Problem constants
#define CHELEM 131072        // 2048*64 elements per chunk (flat-reshape chunk)

typedef __attribute__((ext_vector_type(4))) float   f32x4;
typedef __attribute__((ext_vector_type(8))) short   bh8;     // 8 bf16 in 4 VGPRs
typedef __attribute__((ext_vector_type(4))) unsigned short u16x4;
typedef unsigned short u16;

__device__ inline u16 f2bf(float f) {
    union { float f; uint32_t u; } v; v.f = f;
    uint32_t u = v.u;
    u += 0x7FFF + ((u >> 16) & 1);         // RNE
    return (u16)(u >> 16);
}
__device__ inline float bf2f(u16 h) {
    union { uint32_t u; float f; } v; v.u = ((uint32_t)h) << 16;
    return v.f;
}

__device__ inline void gload_lds16(const u16* g, u16* l) {
    __builtin_amdgcn_global_load_lds(
        (const __attribute__((address_space(1))) uint32_t*)g,
        (__attribute__((address_space(3)))       uint32_t*)l,
        16, 0, 0);
}

// ---------------- K0: convert x, Wq, Wk, Wv to bf16 ----------------
__global__ __launch_bounds__(256) void k0_convert(
        const float* __restrict__ x,
        const float* __restrict__ Wq,
        const float* __restrict__ Wk,
        const float* __restrict__ Wv,
        u16* __restrict__ xb, u16* __restrict__ Wb) {
    int idx = blockIdx.x * 256 + threadIdx.x;   // float4 index, 720896 total
    const float4* src; u16* dst; int off;
    if (idx < 524288) { src = (const float4*)x; dst = xb; off = idx; }
    else {
        int j = idx - 524288;
        int w = j >> 16;                        // 65536 float4 per W
        off = j & 65535;
        src = (const float4*)(w == 0 ? Wq : (w == 1 ? Wk : Wv));
        dst = Wb + w * 262144;
    }
    float4 f = src[off];
    u16x4 o;
    o[0] = f2bf(f.x); o[1] = f2bf(f.y); o[2] = f2bf(f.z); o[3] = f2bf(f.w);
    *(u16x4*)(dst + off * 4) = o;
}

// ---------------- K1: QKV projection GEMM ----------------
// C[m,n] = sum_k xb[m,k] * W[n,k] + bias[n]   (gemm_bt)
// RETILED vs R2: 64x128 tile (was 128x128), BK=64 -> 768 blocks = 3/CU
// (was 384 = 1.5/CU). Same 16 MFMA per wave per K-step; half per-block
// latency; 3-deep co-residency hides the 2-phase barrier drain (m114).
__global__ __launch_bounds__(256) void k1_qkv(
        const u16* __restrict__ xb, const u16* __restrict__ Wb,
        const float* __restrict__ bq, const float* __restrict__ bk,
        const float* __restrict__ bv,
        u16* __restrict__ Qb, u16* __restrict__ Kb, u16* __restrict__ Vb) {
    __shared__ u16 lA[64 * 64];                 // 8 KB
    __shared__ u16 lB[128 * 64];                // 16 KB
    const int tid  = threadIdx.x;
    const int lane = tid & 63, wid = tid >> 6;
    const int wr = wid >> 1, wc = wid & 1;      // wave owns 32 rows x 64 cols
    // XCD swizzle: 768 blocks, 8 XCDs, 96 consecutive per XCD;
    // consecutive swz share mb (A-panel) -> per-XCD L2 locality.
    const int swz  = (blockIdx.x & 7) * 96 + (blockIdx.x >> 3);
    const int mb = swz / 12, nb = swz % 12;
    const int w    = nb >> 2;
    const int nloc = (nb & 3) * 128;
    const u16*   W    = Wb + w * 262144;
    const float* bias = (w == 0) ? bq : ((w == 1) ? bk : bv);
    u16*         out  = (w == 0) ? Qb : ((w == 1) ? Kb : Vb);
    const int m0 = mb * 64;

    f32x4 acc[2][4] = {};
    const int srow = tid >> 3;                  // 0..31
    const int scol = (tid & 7) * 8;

    for (int kb = 0; kb < 8; ++kb) {
        __syncthreads();
        const int k0 = kb * 64;
#pragma unroll
        for (int it = 0; it < 2; ++it) {        // A: 64 rows
            int r = it * 32 + srow;
            gload_lds16(xb + (size_t)(m0 + r) * 512 + k0 + scol, lA + r * 64 + scol);
        }
#pragma unroll
        for (int it = 0; it < 4; ++it) {        // B: 128 rows
            int r = it * 32 + srow;
            gload_lds16(W + (size_t)(nloc + r) * 512 + k0 + scol, lB + r * 64 + scol);
        }
        asm volatile("s_waitcnt vmcnt(0)" ::: "memory");
        __syncthreads();
#pragma unroll
        for (int ks = 0; ks < 2; ++ks) {
            const int kk = ks * 32 + (lane >> 4) * 8;
            bh8 a[2], b[4];
#pragma unroll
            for (int i = 0; i < 2; ++i)
                a[i] = *(const bh8*)&lA[(wr * 32 + i * 16 + (lane & 15)) * 64 + kk];
#pragma unroll
            for (int j = 0; j < 4; ++j)
                b[j] = *(const bh8*)&lB[(wc * 64 + j * 16 + (lane & 15)) * 64 + kk];
#pragma unroll
            for (int i = 0; i < 2; ++i)
#pragma unroll
                for (int j = 0; j < 4; ++j)
                    acc[i][j] = __builtin_amdgcn_mfma_f32_16x16x32_bf16(a[i], b[j], acc[i][j], 0, 0, 0);
        }
    }
#pragma unroll
    for (int i = 0; i < 2; ++i) {
        const int row_base = m0 + wr * 32 + i * 16 + ((lane >> 4) * 4);
#pragma unroll
        for (int j = 0; j < 4; ++j) {
            const int col = nloc + wc * 64 + j * 16 + (lane & 15);
            const float bv_ = bias[col];
#pragma unroll
            for (int r = 0; r < 4; ++r)
                out[(size_t)(row_base + r) * 512 + col] = f2bf(acc[i][j][r] + bv_);
        }
    }
}

// ---------------- K2a: P partials, part[(c*16+s)][d][e] = sum_r V_c[r][d] K_c[r][e] ----------------
__global__ __launch_bounds__(256) void k2a_partials(
        const u16* __restrict__ Kb, const u16* __restrict__ Vb,
        float* __restrict__ part) {
    __shared__ u16 lK[64 * 64];
    __shared__ u16 lV[64 * 64];
    const int tid = threadIdx.x;
    const int c = blockIdx.x >> 4;
    const int s = blockIdx.x & 15;
    const int e4 = (tid & 15) * 4;
    const int d4 = (tid >> 4) * 4;
    float acc[4][4] = {};
    const int base = c * CHELEM + s * 8192;

    for (int step = 0; step < 2; ++step) {
        __syncthreads();
        const int tb = base + step * 4096;
        gload_lds16(Kb + tb + tid * 8,        lK + tid * 8);
        gload_lds16(Kb + tb + 2048 + tid * 8, lK + 2048 + tid * 8);
        gload_lds16(Vb + tb + tid * 8,        lV + tid * 8);
        gload_lds16(Vb + tb + 2048 + tid * 8, lV + 2048 + tid * 8);
        asm volatile("s_waitcnt vmcnt(0)" ::: "memory");
        __syncthreads();
#pragma unroll 8
        for (int r = 0; r < 64; ++r) {
            u16x4 ku = *(const u16x4*)&lK[r * 64 + e4];
            u16x4 vu = *(const u16x4*)&lV[r * 64 + d4];
            float kf[4] = {bf2f(ku[0]), bf2f(ku[1]), bf2f(ku[2]), bf2f(ku[3])};
            float vf[4] = {bf2f(vu[0]), bf2f(vu[1]), bf2f(vu[2]), bf2f(vu[3])};
#pragma unroll
            for (int j = 0; j < 4; ++j)
#pragma unroll
                for (int i = 0; i < 4; ++i)
                    acc[j][i] += vf[j] * kf[i];
        }
    }
    float* dst = part + (size_t)blockIdx.x * 4096;
#pragma unroll
    for (int j = 0; j < 4; ++j)
#pragma unroll
        for (int i = 0; i < 4; ++i)
            dst[(d4 + j) * 64 + (e4 + i)] = acc[j][i];
}

// ---------------- K2b: reduce partials + scale -> Pb bf16 [16][64][64] ----------------
__global__ __launch_bounds__(256) void k2b_reduce(
        const float* __restrict__ part, u16* __restrict__ Pb) {
    const int idx = blockIdx.x * 256 + threadIdx.x;   // 16384 groups of 4 elems
    const int c = idx >> 10;
    const int off = (idx & 1023) * 4;
    f32x4 acc = {0.f, 0.f, 0.f, 0.f};
#pragma unroll
    for (int s = 0; s < 16; ++s)
        acc += *(const f32x4*)&part[(size_t)(c * 16 + s) * 4096 + off];
    u16x4 o;
#pragma unroll
    for (int j = 0; j < 4; ++j) o[j] = f2bf(acc[j] * 0.125f);   // scale = DIM^-0.5
    *(u16x4*)&Pb[c * 4096 + off] = o;
}

// ---------------- K3: out_c = Q_c @ P_c^T  (K=64 per head, no LDS) ----------------
__global__ __launch_bounds__(256) void k3_out(
        const u16* __restrict__ Qb, const u16* __restrict__ Pb,
        float* __restrict__ outp) {
    const int tid = threadIdx.x;
    const int lane = tid & 63, w = tid >> 6;
    const int bb = blockIdx.x >> 6;          // 128 blocks: 64 row-blocks per bb
    const int ib = blockIdx.x & 63;
    const int i0 = ib * 32 + (w >> 1) * 16;
    const int dbase = (w & 1) * 32;
    const int krow = lane & 15;
    const int koff = (lane >> 4) * 8;

    f32x4 acc[8][2] = {};                    // [head][nf]
#pragma unroll
    for (int h = 0; h < 8; ++h) {
        const int c = h * 2 + bb;
        const u16* Qc = Qb + (size_t)c * CHELEM;
        const u16* Pc = Pb + c * 4096;
#pragma unroll
        for (int ks = 0; ks < 2; ++ks) {
            bh8 a = *(const bh8*)&Qc[(i0 + krow) * 64 + ks * 32 + koff];
#pragma unroll
            for (int nf = 0; nf < 2; ++nf) {
                bh8 b = *(const bh8*)&Pc[(dbase + nf * 16 + krow) * 64 + ks * 32 + koff];
                acc[h][nf] = __builtin_amdgcn_mfma_f32_16x16x32_bf16(a, b, acc[h][nf], 0, 0, 0);
            }
        }
    }
    const int orow_base = bb * 2048 + ib * 32 + (w >> 1) * 16 + (lane >> 4) * 4;
#pragma unroll
    for (int nf = 0; nf < 2; ++nf) {
        const int d = dbase + nf * 16 + (lane & 15);
#pragma unroll
        for (int r = 0; r < 4; ++r) {
            f32x4 lo = {acc[0][nf][r], acc[1][nf][r], acc[2][nf][r], acc[3][nf][r]};
            f32x4 hi = {acc[4][nf][r], acc[5][nf][r], acc[6][nf][r], acc[7][nf][r]};
            float* dst = outp + (size_t)(orow_base + r) * 512 + d * 8;
            *(f32x4*)dst = lo;
            *(f32x4*)(dst + 4) = hi;
        }
    }
}

extern "C" void kernel_launch(void* const* d_in, const int* in_sizes, int n_in,
                              void* d_out, int out_size, void* d_ws, size_t ws_size,
                              hipStream_t stream) {
    const float* x  = (const float*)d_in[0];
    const float* Wq = (const float*)d_in[1];
    const float* bq = (const float*)d_in[2];
    const float* Wk = (const float*)d_in[3];
    const float* bk = (const float*)d_in[4];
    const float* Wv = (const float*)d_in[5];
    const float* bv = (const float*)d_in[6];
    float* outp = (float*)d_out;

    u16* xb = (u16*)d_ws;                 // 4096*512
    u16* Wb = xb + 2097152;               // 3*512*512
    u16* Qb = Wb + 786432;                // 4096*512 (flat)
    u16* Kb = Qb + 2097152;               // flat
    u16* Vb = Kb + 2097152;               // flat
    float* part = (float*)(Vb + 2097152); // 256*4096 floats
    u16* Pb = (u16*)(part + 1048576);     // 16*64*64

    k0_convert<<<2816, 256, 0, stream>>>(x, Wq, Wk, Wv, xb, Wb);
    k1_qkv<<<768, 256, 0, stream>>>(xb, Wb, bq, bk, bv, Qb, Kb, Vb);
    k2a_partials<<<256, 256, 0, stream>>>(Kb, Vb, part);
    k2b_reduce<<<64, 256, 0, stream>>>(part, Pb);
    k3_out<<<128, 256, 0, stream>>>(Qb, Pb, outp);
}

// Round 8
// 41.203 us; speedup vs baseline: 5.5011x; 1.1135x over previous
//
#include <hip/hip_runtime.h>
#include <stdint.h>

// Problem constants
#define CHELEM 131072        // 2048*64 elements per chunk (flat-reshape chunk)

typedef __attribute__((ext_vector_type(4))) float   f32x4;
typedef __attribute__((ext_vector_type(8))) short   bh8;     // 8 bf16 in 4 VGPRs
typedef __attribute__((ext_vector_type(4))) unsigned short u16x4;
typedef __attribute__((ext_vector_type(8))) unsigned short u16x8;
typedef unsigned short u16;

__device__ inline u16 f2bf(float f) {
    union { float f; uint32_t u; } v; v.f = f;
    uint32_t u = v.u;
    u += 0x7FFF + ((u >> 16) & 1);         // RNE
    return (u16)(u >> 16);
}

__device__ inline void gload_lds16(const u16* g, u16* l) {
    __builtin_amdgcn_global_load_lds(
        (const __attribute__((address_space(1))) uint32_t*)g,
        (__attribute__((address_space(3)))       uint32_t*)l,
        16, 0, 0);
}

// ---------------- K0: convert x, Wq, Wk, Wv to bf16 ----------------
__global__ __launch_bounds__(256) void k0_convert(
        const float* __restrict__ x,
        const float* __restrict__ Wq,
        const float* __restrict__ Wk,
        const float* __restrict__ Wv,
        u16* __restrict__ xb, u16* __restrict__ Wb) {
    int idx = blockIdx.x * 256 + threadIdx.x;   // float4 index, 720896 total
    const float4* src; u16* dst; int off;
    if (idx < 524288) { src = (const float4*)x; dst = xb; off = idx; }
    else {
        int j = idx - 524288;
        int w = j >> 16;                        // 65536 float4 per W
        off = j & 65535;
        src = (const float4*)(w == 0 ? Wq : (w == 1 ? Wk : Wv));
        dst = Wb + w * 262144;
    }
    float4 f = src[off];
    u16x4 o;
    o[0] = f2bf(f.x); o[1] = f2bf(f.y); o[2] = f2bf(f.z); o[3] = f2bf(f.w);
    *(u16x4*)(dst + off * 4) = o;
}

// ---------------- K1: QKV projection GEMM ----------------
// C[m,n] = sum_k xb[m,k]*W[n,k] + bias[n]  (gemm_bt), 64x128 tile (R7 winner),
// 768 blocks = 3/CU. Q (w==0): straight [4096][512].
// K,V (w==1,2): TRANSPOSED per chunk into Kt2[c][d][g][q]:
//   value at (m, f): c=m>>8, d=f&63, g=f>>6 (in [0,8)), q=m&255.
//   Chunk row r = q*8+g is a bijection <-> (g,q), identical for K and V,
//   so K2's contraction sum_r == sum_{g,q} exactly (R3-verified layout).
__global__ __launch_bounds__(256) void k1_qkv(
        const u16* __restrict__ xb, const u16* __restrict__ Wb,
        const float* __restrict__ bq, const float* __restrict__ bk,
        const float* __restrict__ bv,
        u16* __restrict__ Qb, u16* __restrict__ Kb, u16* __restrict__ Vb) {
    __shared__ u16 smem[12288];                 // 24KB: lA[4096]+lB[8192]; epi tile[64][130] aliases
    u16* lA = smem;
    u16* lB = smem + 4096;
    const int tid  = threadIdx.x;
    const int lane = tid & 63, wid = tid >> 6;
    const int wr = wid >> 1, wc = wid & 1;      // wave owns 32 rows x 64 cols
    const int swz  = (blockIdx.x & 7) * 96 + (blockIdx.x >> 3);   // XCD swizzle
    const int mb = swz / 12, nb = swz % 12;
    const int w    = nb >> 2;
    const int nloc = (nb & 3) * 128;
    const u16*   W    = Wb + w * 262144;
    const float* bias = (w == 0) ? bq : ((w == 1) ? bk : bv);
    u16*         out  = (w == 0) ? Qb : ((w == 1) ? Kb : Vb);
    const int m0 = mb * 64;

    f32x4 acc[2][4] = {};
    const int srow = tid >> 3;                  // 0..31
    const int scol = (tid & 7) * 8;

    for (int kb = 0; kb < 8; ++kb) {
        __syncthreads();
        const int k0 = kb * 64;
#pragma unroll
        for (int it = 0; it < 2; ++it) {        // A: 64 rows
            int r = it * 32 + srow;
            gload_lds16(xb + (size_t)(m0 + r) * 512 + k0 + scol, lA + r * 64 + scol);
        }
#pragma unroll
        for (int it = 0; it < 4; ++it) {        // B: 128 rows
            int r = it * 32 + srow;
            gload_lds16(W + (size_t)(nloc + r) * 512 + k0 + scol, lB + r * 64 + scol);
        }
        asm volatile("s_waitcnt vmcnt(0)" ::: "memory");
        __syncthreads();
#pragma unroll
        for (int ks = 0; ks < 2; ++ks) {
            const int kk = ks * 32 + (lane >> 4) * 8;
            bh8 a[2], b[4];
#pragma unroll
            for (int i = 0; i < 2; ++i)
                a[i] = *(const bh8*)&lA[(wr * 32 + i * 16 + (lane & 15)) * 64 + kk];
#pragma unroll
            for (int j = 0; j < 4; ++j)
                b[j] = *(const bh8*)&lB[(wc * 64 + j * 16 + (lane & 15)) * 64 + kk];
#pragma unroll
            for (int i = 0; i < 2; ++i)
#pragma unroll
                for (int j = 0; j < 4; ++j)
                    acc[i][j] = __builtin_amdgcn_mfma_f32_16x16x32_bf16(a[i], b[j], acc[i][j], 0, 0, 0);
        }
    }

    if (w == 0) {
        // straight store (Q)
#pragma unroll
        for (int i = 0; i < 2; ++i) {
            const int row_base = m0 + wr * 32 + i * 16 + ((lane >> 4) * 4);
#pragma unroll
            for (int j = 0; j < 4; ++j) {
                const int col = nloc + wc * 64 + j * 16 + (lane & 15);
                const float bv_ = bias[col];
#pragma unroll
                for (int r = 0; r < 4; ++r)
                    out[(size_t)(row_base + r) * 512 + col] = f2bf(acc[i][j][r] + bv_);
            }
        }
    } else {
        // transposed store (K,V): stage to padded LDS tile, scatter to Kt2[c][d][g][q]
        __syncthreads();                        // main-loop LDS reads done
        u16 (*tile)[130] = (u16(*)[130])smem;
#pragma unroll
        for (int i = 0; i < 2; ++i) {
            const int ml = wr * 32 + i * 16 + ((lane >> 4) * 4);
#pragma unroll
            for (int j = 0; j < 4; ++j) {
                const int nl = wc * 64 + j * 16 + (lane & 15);
                const float bv_ = bias[nloc + nl];
#pragma unroll
                for (int r = 0; r < 4; ++r)
                    tile[ml + r][nl] = f2bf(acc[i][j][r] + bv_);
            }
        }
        __syncthreads();
        const int ncol  = tid & 127;            // local n col (0..127)
        const int mhalf = tid >> 7;             // 0..1 -> 32-row half
        const int g = (nb & 3) * 2 + (ncol >> 6);
        const int d = ncol & 63;
        const int c = mb >> 2;
        const int qbase = (mb & 3) * 64 + mhalf * 32;
        u16* dst = out + (size_t)c * CHELEM + d * 2048 + g * 256 + qbase;
#pragma unroll
        for (int v = 0; v < 4; ++v) {
            u16x8 t;
#pragma unroll
            for (int j = 0; j < 8; ++j)
                t[j] = tile[mhalf * 32 + v * 8 + j][ncol];
            *(u16x8*)(dst + v * 8) = t;
        }
    }
}

// ---------------- K2: Pb[c][d][e] = scale * sum_k Vt2[c][d][k] * Kt2[c][e][k] ----------------
// 256 blocks: c = bid%16 (-> chunk's 16 blocks share one XCD L2), sub = bid/16
// picks a 16x16 (d,e) subtile. 4 waves split K=2048; frags direct from global
// (k-contiguous, no LDS staging, no loop barriers); 4-way LDS reduce at end.
__global__ __launch_bounds__(256) void k2_pmat(
        const u16* __restrict__ Kt2, const u16* __restrict__ Vt2,
        u16* __restrict__ Pb) {
    __shared__ float red[4][16][16];
    const int tid = threadIdx.x;
    const int lane = tid & 63, w = tid >> 6;
    const int c   = blockIdx.x & 15;
    const int sub = blockIdx.x >> 4;
    const int dq = sub >> 2, eq = sub & 3;
    const u16* Vc = Vt2 + (size_t)c * CHELEM;
    const u16* Kc = Kt2 + (size_t)c * CHELEM;
    const int krow = lane & 15;
    const int arow = (dq * 16 + krow) * 2048;
    const int brow = (eq * 16 + krow) * 2048;
    const int kb = w * 512 + (lane >> 4) * 8;

    f32x4 acc = {};
#pragma unroll
    for (int kt = 0; kt < 16; ++kt) {
        const int k0 = kb + kt * 32;
        bh8 a = *(const bh8*)&Vc[arow + k0];
        bh8 b = *(const bh8*)&Kc[brow + k0];
        acc = __builtin_amdgcn_mfma_f32_16x16x32_bf16(a, b, acc, 0, 0, 0);
    }
#pragma unroll
    for (int r = 0; r < 4; ++r)
        red[w][(lane >> 4) * 4 + r][lane & 15] = acc[r];
    __syncthreads();
    const int row = tid >> 4, col = tid & 15;   // 256 threads cover 16x16
    float s = red[0][row][col] + red[1][row][col] + red[2][row][col] + red[3][row][col];
    Pb[c * 4096 + (dq * 16 + row) * 64 + eq * 16 + col] = f2bf(s * 0.125f);  // scale = DIM^-0.5
}

// ---------------- K3: out_c = Q_c @ P_c^T  (K=64 per head, no LDS) ----------------
__global__ __launch_bounds__(256) void k3_out(
        const u16* __restrict__ Qb, const u16* __restrict__ Pb,
        float* __restrict__ outp) {
    const int tid = threadIdx.x;
    const int lane = tid & 63, w = tid >> 6;
    const int bb = blockIdx.x >> 6;          // 128 blocks: 64 row-blocks per bb
    const int ib = blockIdx.x & 63;
    const int i0 = ib * 32 + (w >> 1) * 16;
    const int dbase = (w & 1) * 32;
    const int krow = lane & 15;
    const int koff = (lane >> 4) * 8;

    f32x4 acc[8][2] = {};                    // [head][nf]
#pragma unroll
    for (int h = 0; h < 8; ++h) {
        const int c = h * 2 + bb;
        const u16* Qc = Qb + (size_t)c * CHELEM;
        const u16* Pc = Pb + c * 4096;
#pragma unroll
        for (int ks = 0; ks < 2; ++ks) {
            bh8 a = *(const bh8*)&Qc[(i0 + krow) * 64 + ks * 32 + koff];
#pragma unroll
            for (int nf = 0; nf < 2; ++nf) {
                bh8 b = *(const bh8*)&Pc[(dbase + nf * 16 + krow) * 64 + ks * 32 + koff];
                acc[h][nf] = __builtin_amdgcn_mfma_f32_16x16x32_bf16(a, b, acc[h][nf], 0, 0, 0);
            }
        }
    }
    const int orow_base = bb * 2048 + ib * 32 + (w >> 1) * 16 + (lane >> 4) * 4;
#pragma unroll
    for (int nf = 0; nf < 2; ++nf) {
        const int d = dbase + nf * 16 + (lane & 15);
#pragma unroll
        for (int r = 0; r < 4; ++r) {
            f32x4 lo = {acc[0][nf][r], acc[1][nf][r], acc[2][nf][r], acc[3][nf][r]};
            f32x4 hi = {acc[4][nf][r], acc[5][nf][r], acc[6][nf][r], acc[7][nf][r]};
            float* dst = outp + (size_t)(orow_base + r) * 512 + d * 8;
            *(f32x4*)dst = lo;
            *(f32x4*)(dst + 4) = hi;
        }
    }
}

extern "C" void kernel_launch(void* const* d_in, const int* in_sizes, int n_in,
                              void* d_out, int out_size, void* d_ws, size_t ws_size,
                              hipStream_t stream) {
    const float* x  = (const float*)d_in[0];
    const float* Wq = (const float*)d_in[1];
    const float* bq = (const float*)d_in[2];
    const float* Wk = (const float*)d_in[3];
    const float* bk = (const float*)d_in[4];
    const float* Wv = (const float*)d_in[5];
    const float* bv = (const float*)d_in[6];
    float* outp = (float*)d_out;

    u16* xb = (u16*)d_ws;                 // 4096*512
    u16* Wb = xb + 2097152;               // 3*512*512
    u16* Qb = Wb + 786432;                // 4096*512 (straight)
    u16* Kb = Qb + 2097152;               // Kt2 transposed chunks
    u16* Vb = Kb + 2097152;               // Vt2 transposed chunks
    u16* Pb = Vb + 2097152;               // 16*64*64

    k0_convert<<<2816, 256, 0, stream>>>(x, Wq, Wk, Wv, xb, Wb);
    k1_qkv<<<768, 256, 0, stream>>>(xb, Wb, bq, bk, bv, Qb, Kb, Vb);
    k2_pmat<<<256, 256, 0, stream>>>(Kb, Vb, Pb);
    k3_out<<<128, 256, 0, stream>>>(Qb, Pb, outp);
}